// Round 1
// baseline (229.857 us; speedup 1.0000x reference)
//
#include <hip/hip_runtime.h>
#include <hip/hip_bf16.h>

#define N_NODES 50000
#define N_EDGES 800000
#define NBUK 512            // col-range buckets
#define BWID 98             // cols per bucket: 512*98 = 50176 >= N
#define BCAP 2048           // entries cap/bucket (mean 1562, +12 sigma)
#define PCHUNK 1024         // edges per partition block (was 2048: only 1.5 blk/CU)
#define PBLK 782            // ceil(800000/1024)

typedef __bf16 bf16x8 __attribute__((ext_vector_type(8)));
typedef float f32x4 __attribute__((ext_vector_type(4)));

__device__ __forceinline__ unsigned short f2bf(float f) {
    unsigned int u = __builtin_bit_cast(unsigned int, f);
    u += 0x7fffu + ((u >> 16) & 1u);   // round-to-nearest-even
    return (unsigned short)(u >> 16);
}
__device__ __forceinline__ float bf2f(unsigned short s) {
    return __uint_as_float((unsigned int)s << 16);
}

// ---------------- Wvbar prep: head-averaged Wv -> bf16, MFMA-frag-swizzled ----
// element (d,c) -> frag ks=c>>5, nf=d>>4, lane = ((c>>3)&3)*16 + (d&15), j=c&7
// stored at ((ks*4+nf)*64 + lane)*8 + j  (so a wave's b-frag load is 1 KB coalesced)
__global__ __launch_bounds__(256) void k_wprep(const float* __restrict__ Wv,
                                               const float* __restrict__ bv,
                                               unsigned short* __restrict__ wvbar,
                                               float* __restrict__ bvbar) {
    int idx = blockIdx.x * 256 + threadIdx.x;   // 16 blocks -> 4096, 4 cols each
    int d = idx >> 6;
    int c0 = (idx & 63) * 4;
    const float4* W4 = (const float4*)Wv;
    float4 w0 = W4[((d) * 256 + c0) >> 2];
    float4 w1 = W4[((64 + d) * 256 + c0) >> 2];
    float4 w2 = W4[((128 + d) * 256 + c0) >> 2];
    float4 w3 = W4[((192 + d) * 256 + c0) >> 2];
    ushort4 s;
    s.x = f2bf(0.25f * (w0.x + w1.x + w2.x + w3.x));
    s.y = f2bf(0.25f * (w0.y + w1.y + w2.y + w3.y));
    s.z = f2bf(0.25f * (w0.z + w1.z + w2.z + w3.z));
    s.w = f2bf(0.25f * (w0.w + w1.w + w2.w + w3.w));
    int ks = c0 >> 5;
    int q  = (c0 >> 3) & 3;
    int j0 = c0 & 7;                            // 0 or 4 -> ushort4 stays contiguous
    int nf = d >> 4;
    int ln = d & 15;
    int base = ((ks * 4 + nf) * 64 + q * 16 + ln) * 8 + j0;
    *(ushort4*)&wvbar[base] = s;
    if (blockIdx.x == 0 && threadIdx.x < 64) {
        int t = threadIdx.x;
        bvbar[t] = 0.25f * (bv[t] + bv[64 + t] + bv[128 + t] + bv[192 + t]);
    }
}

// ---------------- edge partition into 512 col-range buckets ----------------
// entry = { row<<16 | bf16(w), lcol };  block-contiguous runs per bucket region.
__global__ __launch_bounds__(256) void k_part(const int* __restrict__ ei,
                                              const float* __restrict__ ew,
                                              int* __restrict__ gcur,
                                              uint2* __restrict__ bkt)
{
    __shared__ int hist[NBUK];
    __shared__ int cur[NBUK];
    const int t = threadIdx.x;
    const int e0 = blockIdx.x * PCHUNK;
    hist[t] = 0; hist[t + 256] = 0;
    __syncthreads();
    #pragma unroll
    for (int k = 0; k < PCHUNK / 256; ++k) {
        int e = e0 + k * 256 + t;
        if (e < N_EDGES) {
            int c = ei[N_EDGES + e];
            atomicAdd(&hist[c / BWID], 1);
        }
    }
    __syncthreads();
    {
        int b = t;
        if (hist[b]) cur[b] = b * BCAP + atomicAdd(&gcur[b], hist[b]);
        b = t + 256;
        if (hist[b]) cur[b] = b * BCAP + atomicAdd(&gcur[b], hist[b]);
    }
    __syncthreads();
    #pragma unroll
    for (int k = 0; k < PCHUNK / 256; ++k) {
        int e = e0 + k * 256 + t;
        if (e < N_EDGES) {
            int c = ei[N_EDGES + e];
            int b = c / BWID;
            int row = ei[e];
            float w = ew[e];
            int slot = atomicAdd(&cur[b], 1);
            if (slot < (b + 1) * BCAP) {
                uint2 en;
                en.x = ((unsigned int)row << 16) | (unsigned int)f2bf(w);
                en.y = (unsigned int)(c - b * BWID);
                bkt[slot] = en;
            }
        }
    }
}

// ---------------- per-bucket: deg + off (into padded layout) + in-bucket sort --
__global__ __launch_bounds__(256) void k_bucket(const int* __restrict__ gcur,
                                                const uint2* __restrict__ bkt,
                                                int* __restrict__ deg,
                                                int* __restrict__ off,
                                                unsigned int* __restrict__ srt)
{
    __shared__ int hist[128];       // >= BWID
    __shared__ int lcur[128];
    const int t = threadIdx.x;
    const int b = blockIdx.x;
    if (t < 128) hist[t] = 0;
    __syncthreads();
    const int cnt = min(gcur[b], BCAP);
    const uint2* base = bkt + (size_t)b * BCAP;
    for (int i = t; i < cnt; i += 256)
        atomicAdd(&hist[base[i].y], 1);
    __syncthreads();
    // exclusive scan over 128 — ALL threads execute every barrier (t>=128 idle)
    const int v = (t < 128) ? hist[t] : 0;
    #pragma unroll
    for (int d = 1; d < 128; d <<= 1) {
        int u = (t >= d && t < 128) ? hist[t - d] : 0;
        __syncthreads();
        if (t >= d && t < 128) hist[t] += u;
        __syncthreads();
    }
    if (t < 128) {
        int excl = hist[t] - v;
        lcur[t] = excl;
        if (t < BWID) {
            int col = b * BWID + t;
            if (col < N_NODES) {
                deg[col] = v;
                off[col] = b * BCAP + excl;
            }
        }
    }
    __syncthreads();
    unsigned int* sb = srt + (size_t)b * BCAP;
    for (int i = t; i < cnt; i += 256) {
        uint2 en = base[i];
        int pos = atomicAdd(&lcur[en.y], 1);
        sb[pos] = en.x;             // row<<16 | bf16(w)
    }
}

// ---------------- vbar GEMM: fragment-direct from global, no LDS staging -------
// vbarh[n,d] = bf16( (sum_c Xs[n,c]*Wvbar[d,c] + bvbar[d]) * rsqrt(deg[n]) )
// vsumcol[d] += sum_n acc (pre-bias, UNSCALED) for the attention constant.
// Each wave = one 16-row x 64-col tile; A-frag (row=l&15, k=(l>>4)*8+j within
// 32-block) is 8 CONSECUTIVE floats of one X row -> load 2 float4 per ks
// directly to VGPRs, convert in-register. No barriers between waves; all 16
// A-loads issued up-front for MLP.
__global__ __launch_bounds__(256, 3) void k_vbar(
    const float* __restrict__ Xs, const unsigned short* __restrict__ wvbar,
    const float* __restrict__ bvbar, const int* __restrict__ deg,
    unsigned short* __restrict__ vbarh, float* __restrict__ vsumcol)
{
    __shared__ float lvs[64];
    const int t = threadIdx.x;
    const int w = t >> 6;
    const int l = t & 63;
    const int ln = l & 15;
    const int q = l >> 4;
    const int n0 = blockIdx.x * 64;

    if (t < 64) lvs[t] = 0.f;

    // A row this lane feeds (16 consecutive rows per wave)
    const int ga = n0 + w * 16 + ln;
    const bool aok = ga < N_NODES;

    // 64 floats per lane: cols ks*32 + q*8 .. +7  -> float4 idx ga*64 + q*2 + ks*8
    float4 xa[8], xb[8];
    const float4* X4 = (const float4*)Xs;
    const int rb = ga * 64 + q * 2;
    #pragma unroll
    for (int ks = 0; ks < 8; ++ks) {
        if (aok) {
            xa[ks] = X4[rb + ks * 8];
            xb[ks] = X4[rb + ks * 8 + 1];
        } else {
            xa[ks] = (float4){0.f, 0.f, 0.f, 0.f};
            xb[ks] = (float4){0.f, 0.f, 0.f, 0.f};
        }
    }

    f32x4 acc[4];
    #pragma unroll
    for (int nf = 0; nf < 4; ++nf) acc[nf] = (f32x4){0.f, 0.f, 0.f, 0.f};

    const bf16x8* Wf = (const bf16x8*)wvbar;   // frag-swizzled, L2-hot
    #pragma unroll
    for (int ks = 0; ks < 8; ++ks) {
        union { bf16x8 v; ushort4 u4[2]; } A;
        ushort4 s0, s1;
        s0.x = f2bf(xa[ks].x); s0.y = f2bf(xa[ks].y);
        s0.z = f2bf(xa[ks].z); s0.w = f2bf(xa[ks].w);
        s1.x = f2bf(xb[ks].x); s1.y = f2bf(xb[ks].y);
        s1.z = f2bf(xb[ks].z); s1.w = f2bf(xb[ks].w);
        A.u4[0] = s0; A.u4[1] = s1;
        #pragma unroll
        for (int nf = 0; nf < 4; ++nf) {
            bf16x8 b = Wf[(ks * 4 + nf) * 64 + l];
            acc[nf] = __builtin_amdgcn_mfma_f32_16x16x32_bf16(A.v, b, acc[nf], 0, 0, 0);
        }
    }

    // epilogue: D[m = q*4+r4][n = ln]; write bf16 vbar pre-scaled by rsqrt(deg)
    float bvb[4];
    #pragma unroll
    for (int nf = 0; nf < 4; ++nf) bvb[nf] = bvbar[nf * 16 + ln];
    float psum[4] = {0.f, 0.f, 0.f, 0.f};
    #pragma unroll
    for (int r4 = 0; r4 < 4; ++r4) {
        int g = n0 + w * 16 + q * 4 + r4;
        bool ok = g < N_NODES;
        float sc = 0.f;
        if (ok) {
            float dg = (float)deg[g];
            sc = (dg > 0.f) ? __frsqrt_rn(dg) : 0.f;
        }
        #pragma unroll
        for (int nf = 0; nf < 4; ++nf) {
            if (ok) vbarh[g * 64 + nf * 16 + ln] = f2bf((acc[nf][r4] + bvb[nf]) * sc);
            psum[nf] += acc[nf][r4];   // OOB A-rows were zeroed -> acc rows are 0
        }
    }
    __syncthreads();
    #pragma unroll
    for (int nf = 0; nf < 4; ++nf) atomicAdd(&lvs[nf * 16 + ln], psum[nf]);
    __syncthreads();
    if (t < 64) atomicAdd(&vsumcol[t], lvs[t]);
}

// ---------------- GCN gather: one wave per node, lane = d-channel ----------------
// out[n,d] = aconst[d] + rsqrt(deg[n]) * sum_e w_e * vbarh[row_e, d]
__global__ __launch_bounds__(256) void k_gather(
    const int* __restrict__ off, const int* __restrict__ deg,
    const unsigned int* __restrict__ srt, const unsigned short* __restrict__ vbarh,
    const float* __restrict__ vsumcol, const float* __restrict__ bvbar,
    float* __restrict__ out)
{
    const int t = threadIdx.x;
    const int lane = t & 63;
    const int n = blockIdx.x * 4 + (t >> 6);          // grid: 12544 blocks -> 50176
    if (n >= N_NODES) return;                          // whole wave exits together
    const int e0 = off[n];
    const int dc = deg[n];
    const int e1 = e0 + dc;
    float acc = 0.f;
    int e = e0;
    for (; e + 3 < e1; e += 4) {
        unsigned int p0 = srt[e];
        unsigned int p1 = srt[e + 1];
        unsigned int p2 = srt[e + 2];
        unsigned int p3 = srt[e + 3];
        float a0 = __uint_as_float(p0 << 16) * bf2f(vbarh[(p0 >> 16) * 64 + lane]);
        float a1 = __uint_as_float(p1 << 16) * bf2f(vbarh[(p1 >> 16) * 64 + lane]);
        float a2 = __uint_as_float(p2 << 16) * bf2f(vbarh[(p2 >> 16) * 64 + lane]);
        float a3 = __uint_as_float(p3 << 16) * bf2f(vbarh[(p3 >> 16) * 64 + lane]);
        acc += (a0 + a1) + (a2 + a3);
    }
    for (; e < e1; ++e) {
        unsigned int p = srt[e];
        acc += __uint_as_float(p << 16) * bf2f(vbarh[(p >> 16) * 64 + lane]);
    }
    float dcf = (float)dc;
    float scn = (dcf > 0.f) ? __frsqrt_rn(dcf) : 0.f;
    float aconst = vsumcol[lane] * (1.0f / (float)N_NODES) + bvbar[lane];
    out[n * 64 + lane] = acc * scn + aconst;
}

extern "C" void kernel_launch(void* const* d_in, const int* in_sizes, int n_in,
                              void* d_out, int out_size, void* d_ws, size_t ws_size,
                              hipStream_t stream)
{
    const float* Xs = (const float*)d_in[1];   // source_input [N,256]
    const float* Wv = (const float*)d_in[6];   // Wv_w [256,256]
    const float* bv = (const float*)d_in[7];   // Wv_b [256]
    const int*   ei = (const int*)d_in[8];     // edge_index [2,E]
    const float* ew = (const float*)d_in[9];   // edge_weight [E]
    float* out = (float*)d_out;                // [N,64]

    unsigned short* vbarh = (unsigned short*)d_ws;               // 3.2M bf16 (6.4 MB)
    uint2* bkt  = (uint2*)(vbarh + (size_t)N_NODES * 64);        // 512*2048*8 = 8.39 MB
    unsigned int* srt = (unsigned int*)(bkt + (size_t)NBUK * BCAP); // 4.19 MB
    unsigned short* wvbar = (unsigned short*)(srt + (size_t)NBUK * BCAP); // 32 KB
    float* bvbar   = (float*)(wvbar + 16384);                    // 64
    float* vsumcol = bvbar + 64;                                 // 64
    int*   gcur    = (int*)(vsumcol + 64);                       // 512
    int*   deg     = gcur + NBUK;                                // 50,000
    int*   off     = deg + N_NODES;                              // 50,000

    // zero vsumcol + gcur (adjacent); everything else fully written by kernels
    hipMemsetAsync(vsumcol, 0, (size_t)(64 + NBUK) * 4, stream);
    k_wprep<<<16, 256, 0, stream>>>(Wv, bv, wvbar, bvbar);
    k_part<<<PBLK, 256, 0, stream>>>(ei, ew, gcur, bkt);
    k_bucket<<<NBUK, 256, 0, stream>>>(gcur, bkt, deg, off, srt);
    k_vbar<<<(N_NODES + 63) / 64, 256, 0, stream>>>(Xs, wvbar, bvbar, deg, vbarh, vsumcol);
    k_gather<<<(NBUK * BWID) / 4, 256, 0, stream>>>(off, deg, srt, vbarh, vsumcol, bvbar, out);
}

// Round 2
// 219.084 us; speedup vs baseline: 1.0492x; 1.0492x over previous
//
#include <hip/hip_runtime.h>
#include <hip/hip_bf16.h>

#define N_NODES 50000
#define N_EDGES 800000
#define NBUK 512            // col-range buckets
#define BWID 98             // cols per bucket: 512*98 = 50176 >= N
#define BCAP 2048           // entries cap/bucket (mean 1562, +12 sigma)
#define PCHUNK 1024         // edges per partition block
#define PBLK 782            // ceil(800000/1024)
#define NVS 8               // vsumcol replicas (atomic de-contention)

typedef __bf16 bf16x8 __attribute__((ext_vector_type(8)));
typedef float f32x4 __attribute__((ext_vector_type(4)));

__device__ __forceinline__ unsigned short f2bf(float f) {
    unsigned int u = __builtin_bit_cast(unsigned int, f);
    u += 0x7fffu + ((u >> 16) & 1u);   // round-to-nearest-even
    return (unsigned short)(u >> 16);
}
__device__ __forceinline__ float bf2f(unsigned short s) {
    return __uint_as_float((unsigned int)s << 16);
}

// async 16B global->LDS (no VGPR result: compiler cannot serialize these)
__device__ __forceinline__ void gld_lds16(const void* g, void* lds) {
    __builtin_amdgcn_global_load_lds(
        (const __attribute__((address_space(1))) unsigned int*)g,
        (__attribute__((address_space(3))) unsigned int*)lds, 16, 0, 0);
}

// ---------------- Wvbar prep: head-averaged Wv -> bf16, MFMA-frag-swizzled ----
// element (d,c) -> frag ks=c>>5, nf=d>>4, lane = ((c>>3)&3)*16 + (d&15), j=c&7
// stored at ((ks*4+nf)*64 + lane)*8 + j  (so a wave's b-frag load is 1 KB coalesced)
__global__ __launch_bounds__(256) void k_wprep(const float* __restrict__ Wv,
                                               const float* __restrict__ bv,
                                               unsigned short* __restrict__ wvbar,
                                               float* __restrict__ bvbar) {
    int idx = blockIdx.x * 256 + threadIdx.x;   // 16 blocks -> 4096, 4 cols each
    int d = idx >> 6;
    int c0 = (idx & 63) * 4;
    const float4* W4 = (const float4*)Wv;
    float4 w0 = W4[((d) * 256 + c0) >> 2];
    float4 w1 = W4[((64 + d) * 256 + c0) >> 2];
    float4 w2 = W4[((128 + d) * 256 + c0) >> 2];
    float4 w3 = W4[((192 + d) * 256 + c0) >> 2];
    ushort4 s;
    s.x = f2bf(0.25f * (w0.x + w1.x + w2.x + w3.x));
    s.y = f2bf(0.25f * (w0.y + w1.y + w2.y + w3.y));
    s.z = f2bf(0.25f * (w0.z + w1.z + w2.z + w3.z));
    s.w = f2bf(0.25f * (w0.w + w1.w + w2.w + w3.w));
    int ks = c0 >> 5;
    int q  = (c0 >> 3) & 3;
    int j0 = c0 & 7;                            // 0 or 4 -> ushort4 stays contiguous
    int nf = d >> 4;
    int ln = d & 15;
    int base = ((ks * 4 + nf) * 64 + q * 16 + ln) * 8 + j0;
    *(ushort4*)&wvbar[base] = s;
    if (blockIdx.x == 0 && threadIdx.x < 64) {
        int t = threadIdx.x;
        bvbar[t] = 0.25f * (bv[t] + bv[64 + t] + bv[128 + t] + bv[192 + t]);
    }
}

// ---------------- edge partition into 512 col-range buckets ----------------
// entry = { row<<16 | bf16(w), lcol };  block-contiguous runs per bucket region.
__global__ __launch_bounds__(256) void k_part(const int* __restrict__ ei,
                                              const float* __restrict__ ew,
                                              int* __restrict__ gcur,
                                              uint2* __restrict__ bkt)
{
    __shared__ int hist[NBUK];
    __shared__ int cur[NBUK];
    const int t = threadIdx.x;
    const int e0 = blockIdx.x * PCHUNK;
    hist[t] = 0; hist[t + 256] = 0;
    __syncthreads();
    #pragma unroll
    for (int k = 0; k < PCHUNK / 256; ++k) {
        int e = e0 + k * 256 + t;
        if (e < N_EDGES) {
            int c = ei[N_EDGES + e];
            atomicAdd(&hist[c / BWID], 1);
        }
    }
    __syncthreads();
    {
        int b = t;
        if (hist[b]) cur[b] = b * BCAP + atomicAdd(&gcur[b], hist[b]);
        b = t + 256;
        if (hist[b]) cur[b] = b * BCAP + atomicAdd(&gcur[b], hist[b]);
    }
    __syncthreads();
    #pragma unroll
    for (int k = 0; k < PCHUNK / 256; ++k) {
        int e = e0 + k * 256 + t;
        if (e < N_EDGES) {
            int c = ei[N_EDGES + e];
            int b = c / BWID;
            int row = ei[e];
            float w = ew[e];
            int slot = atomicAdd(&cur[b], 1);
            if (slot < (b + 1) * BCAP) {
                uint2 en;
                en.x = ((unsigned int)row << 16) | (unsigned int)f2bf(w);
                en.y = (unsigned int)(c - b * BWID);
                bkt[slot] = en;
            }
        }
    }
}

// ---------------- per-bucket: deg + off (into padded layout) + in-bucket sort --
__global__ __launch_bounds__(256) void k_bucket(const int* __restrict__ gcur,
                                                const uint2* __restrict__ bkt,
                                                int* __restrict__ deg,
                                                int* __restrict__ off,
                                                unsigned int* __restrict__ srt)
{
    __shared__ int hist[128];       // >= BWID
    __shared__ int lcur[128];
    const int t = threadIdx.x;
    const int b = blockIdx.x;
    if (t < 128) hist[t] = 0;
    __syncthreads();
    const int cnt = min(gcur[b], BCAP);
    const uint2* base = bkt + (size_t)b * BCAP;
    for (int i = t; i < cnt; i += 256)
        atomicAdd(&hist[base[i].y], 1);
    __syncthreads();
    // exclusive scan over 128 — ALL threads execute every barrier (t>=128 idle)
    const int v = (t < 128) ? hist[t] : 0;
    #pragma unroll
    for (int d = 1; d < 128; d <<= 1) {
        int u = (t >= d && t < 128) ? hist[t - d] : 0;
        __syncthreads();
        if (t >= d && t < 128) hist[t] += u;
        __syncthreads();
    }
    if (t < 128) {
        int excl = hist[t] - v;
        lcur[t] = excl;
        if (t < BWID) {
            int col = b * BWID + t;
            if (col < N_NODES) {
                deg[col] = v;
                off[col] = b * BCAP + excl;
            }
        }
    }
    __syncthreads();
    unsigned int* sb = srt + (size_t)b * BCAP;
    for (int i = t; i < cnt; i += 256) {
        uint2 en = base[i];
        int pos = atomicAdd(&lcur[en.y], 1);
        sb[pos] = en.x;             // row<<16 | bf16(w)
    }
}

// ---------------- vbar GEMM: global_load_lds staging + swizzled LDS ------------
// vbarh[n,d] = bf16( (sum_c Xs[n,c]*Wvbar[d,c] + bvbar[d]) * rsqrt(deg[n]) )
// vsumcol8[blk&7][d] += sum_n acc (pre-bias, UNSCALED) for the attention const.
// X tile (64 rows x 256 fp32 = 64 KB) staged async; global source is
// pre-swizzled (byte ^ ((row&7)<<4)) so the linear LDS write gives a layout
// where the per-fragment ds_read_b128 is only 2-way bank-aliased (free).
__global__ __launch_bounds__(256) void k_vbar(
    const float* __restrict__ Xs, const unsigned short* __restrict__ wvbar,
    const float* __restrict__ bvbar, const int* __restrict__ deg,
    unsigned short* __restrict__ vbarh, float* __restrict__ vsumcol8)
{
    __shared__ float lX[64 * 256];    // 64 KB, rows XOR-swizzled
    __shared__ float lvs[64];
    const int t = threadIdx.x;
    const int w = t >> 6;
    const int l = t & 63;
    const int ln = l & 15;
    const int q = l >> 4;
    const int n0 = blockIdx.x * 64;

    if (t < 64) lvs[t] = 0.f;

    // --- stage: 16 rows per wave, 1 KB per instruction, all 16 in flight ---
    const char* Xc = (const char*)Xs;
    #pragma unroll
    for (int i = 0; i < 16; ++i) {
        int row = w * 16 + i;                       // wave-uniform
        int g = n0 + row;
        int gc = (g < N_NODES) ? g : 0;             // clamp OOB (finite data; masked later)
        unsigned int swz = ((unsigned int)(row & 7)) << 4;
        const void* src = Xc + (size_t)gc * 1024 + (((unsigned int)(l * 16)) ^ swz);
        gld_lds16(src, &lX[row * 256]);
    }
    __syncthreads();    // compiler emits vmcnt(0) drain before the barrier

    f32x4 acc[4];
    #pragma unroll
    for (int nf = 0; nf < 4; ++nf) acc[nf] = (f32x4){0.f, 0.f, 0.f, 0.f};

    const bf16x8* Wf = (const bf16x8*)wvbar;        // frag-swizzled, L2-hot
    const unsigned int swzl = ((unsigned int)(l & 7)) << 4;   // row = w*16+(l&15)
    const char* lrow = (const char*)&lX[(w * 16 + ln) * 256];

    #pragma unroll
    for (int ks = 0; ks < 8; ++ks) {
        unsigned int c0 = (unsigned int)(ks * 128 + q * 32);
        float4 xa = *(const float4*)(lrow + (c0 ^ swzl));
        float4 xb = *(const float4*)(lrow + ((c0 + 16u) ^ swzl));
        bf16x8 A;
        A[0] = (__bf16)xa.x; A[1] = (__bf16)xa.y;
        A[2] = (__bf16)xa.z; A[3] = (__bf16)xa.w;
        A[4] = (__bf16)xb.x; A[5] = (__bf16)xb.y;
        A[6] = (__bf16)xb.z; A[7] = (__bf16)xb.w;
        #pragma unroll
        for (int nf = 0; nf < 4; ++nf) {
            bf16x8 b = Wf[(ks * 4 + nf) * 64 + l];
            acc[nf] = __builtin_amdgcn_mfma_f32_16x16x32_bf16(A, b, acc[nf], 0, 0, 0);
        }
    }

    // epilogue: D[m = q*4+r4][n = ln]; write bf16 vbar pre-scaled by rsqrt(deg)
    float bvb[4];
    #pragma unroll
    for (int nf = 0; nf < 4; ++nf) bvb[nf] = bvbar[nf * 16 + ln];
    float psum[4] = {0.f, 0.f, 0.f, 0.f};
    #pragma unroll
    for (int r4 = 0; r4 < 4; ++r4) {
        int g = n0 + w * 16 + q * 4 + r4;
        bool ok = g < N_NODES;
        float sc = 0.f;
        if (ok) {
            float dg = (float)deg[g];
            sc = (dg > 0.f) ? __frsqrt_rn(dg) : 0.f;
        }
        #pragma unroll
        for (int nf = 0; nf < 4; ++nf) {
            if (ok) {
                vbarh[g * 64 + nf * 16 + ln] = f2bf((acc[nf][r4] + bvb[nf]) * sc);
                psum[nf] += acc[nf][r4];   // OOB rows hold clamped data: excluded
            }
        }
    }
    #pragma unroll
    for (int nf = 0; nf < 4; ++nf) atomicAdd(&lvs[nf * 16 + ln], psum[nf]);
    __syncthreads();
    if (t < 64) atomicAdd(&vsumcol8[(blockIdx.x & (NVS - 1)) * 64 + t], lvs[t]);
}

// ---------------- GCN gather: one wave per node, lane = d-channel ----------------
// out[n,d] = aconst[d] + rsqrt(deg[n]) * sum_e w_e * vbarh[row_e, d]
__global__ __launch_bounds__(256) void k_gather(
    const int* __restrict__ off, const int* __restrict__ deg,
    const unsigned int* __restrict__ srt, const unsigned short* __restrict__ vbarh,
    const float* __restrict__ vsumcol8, const float* __restrict__ bvbar,
    float* __restrict__ out)
{
    const int t = threadIdx.x;
    const int lane = t & 63;
    const int n = blockIdx.x * 4 + (t >> 6);          // grid: 12544 blocks -> 50176
    if (n >= N_NODES) return;                          // whole wave exits together
    const int e0 = off[n];
    const int dc = deg[n];
    const int e1 = e0 + dc;
    float acc = 0.f;
    int e = e0;
    for (; e + 3 < e1; e += 4) {
        unsigned int p0 = srt[e];
        unsigned int p1 = srt[e + 1];
        unsigned int p2 = srt[e + 2];
        unsigned int p3 = srt[e + 3];
        float a0 = __uint_as_float(p0 << 16) * bf2f(vbarh[(p0 >> 16) * 64 + lane]);
        float a1 = __uint_as_float(p1 << 16) * bf2f(vbarh[(p1 >> 16) * 64 + lane]);
        float a2 = __uint_as_float(p2 << 16) * bf2f(vbarh[(p2 >> 16) * 64 + lane]);
        float a3 = __uint_as_float(p3 << 16) * bf2f(vbarh[(p3 >> 16) * 64 + lane]);
        acc += (a0 + a1) + (a2 + a3);
    }
    for (; e < e1; ++e) {
        unsigned int p = srt[e];
        acc += __uint_as_float(p << 16) * bf2f(vbarh[(p >> 16) * 64 + lane]);
    }
    float dcf = (float)dc;
    float scn = (dcf > 0.f) ? __frsqrt_rn(dcf) : 0.f;
    float vs = 0.f;
    #pragma unroll
    for (int i = 0; i < NVS; ++i) vs += vsumcol8[i * 64 + lane];
    float aconst = vs * (1.0f / (float)N_NODES) + bvbar[lane];
    out[n * 64 + lane] = acc * scn + aconst;
}

extern "C" void kernel_launch(void* const* d_in, const int* in_sizes, int n_in,
                              void* d_out, int out_size, void* d_ws, size_t ws_size,
                              hipStream_t stream)
{
    const float* Xs = (const float*)d_in[1];   // source_input [N,256]
    const float* Wv = (const float*)d_in[6];   // Wv_w [256,256]
    const float* bv = (const float*)d_in[7];   // Wv_b [256]
    const int*   ei = (const int*)d_in[8];     // edge_index [2,E]
    const float* ew = (const float*)d_in[9];   // edge_weight [E]
    float* out = (float*)d_out;                // [N,64]

    unsigned short* vbarh = (unsigned short*)d_ws;               // 3.2M bf16 (6.4 MB)
    uint2* bkt  = (uint2*)(vbarh + (size_t)N_NODES * 64);        // 512*2048*8 = 8.39 MB
    unsigned int* srt = (unsigned int*)(bkt + (size_t)NBUK * BCAP); // 4.19 MB
    unsigned short* wvbar = (unsigned short*)(srt + (size_t)NBUK * BCAP); // 32 KB
    float* bvbar   = (float*)(wvbar + 16384);                    // 64
    float* vsumcol = bvbar + 64;                                 // 8 x 64 replicas
    int*   gcur    = (int*)(vsumcol + NVS * 64);                 // 512
    int*   deg     = gcur + NBUK;                                // 50,000
    int*   off     = deg + N_NODES;                              // 50,000

    // zero vsumcol replicas + gcur (adjacent); rest fully written by kernels
    hipMemsetAsync(vsumcol, 0, (size_t)(NVS * 64 + NBUK) * 4, stream);
    k_wprep<<<16, 256, 0, stream>>>(Wv, bv, wvbar, bvbar);
    k_part<<<PBLK, 256, 0, stream>>>(ei, ew, gcur, bkt);
    k_bucket<<<NBUK, 256, 0, stream>>>(gcur, bkt, deg, off, srt);
    k_vbar<<<(N_NODES + 63) / 64, 256, 0, stream>>>(Xs, wvbar, bvbar, deg, vbarh, vsumcol);
    k_gather<<<(NBUK * BWID) / 4, 256, 0, stream>>>(off, deg, srt, vbarh, vsumcol, bvbar, out);
}

// Round 3
// 215.179 us; speedup vs baseline: 1.0682x; 1.0181x over previous
//
#include <hip/hip_runtime.h>
#include <hip/hip_bf16.h>

#define N_NODES 50000
#define N_EDGES 800000
#define NBUK 512            // col-range buckets
#define BWID 98             // cols per bucket: 512*98 = 50176 >= N
#define BCAP 2048           // entries cap/bucket (mean 1562, +12 sigma)
#define PCHUNK 1024         // edges per partition block
#define PBLK 782            // ceil(800000/1024)
#define NVS 32              // vsumcol replicas (atomic de-contention)

typedef __bf16 bf16x8 __attribute__((ext_vector_type(8)));
typedef float f32x4 __attribute__((ext_vector_type(4)));

__device__ __forceinline__ unsigned short f2bf(float f) {
    unsigned int u = __builtin_bit_cast(unsigned int, f);
    u += 0x7fffu + ((u >> 16) & 1u);   // round-to-nearest-even
    return (unsigned short)(u >> 16);
}
__device__ __forceinline__ float bf2f(unsigned short s) {
    return __uint_as_float((unsigned int)s << 16);
}

// async 16B global->LDS (no VGPR result; LDS dest = wave-uniform base + lane*16)
__device__ __forceinline__ void gld_lds16(const void* g, void* lds) {
    __builtin_amdgcn_global_load_lds(
        (const __attribute__((address_space(1))) unsigned int*)g,
        (__attribute__((address_space(3))) unsigned int*)lds, 16, 0, 0);
}

// ---------------- Wvbar prep: head-averaged Wv -> bf16, MFMA-frag-swizzled ----
// element (d,c) -> frag ks=c>>5, nf=d>>4, lane = ((c>>3)&3)*16 + (d&15), j=c&7
// stored at ((ks*4+nf)*64 + lane)*8 + j  (so a wave's b-frag load is 1 KB coalesced)
__global__ __launch_bounds__(256) void k_wprep(const float* __restrict__ Wv,
                                               const float* __restrict__ bv,
                                               unsigned short* __restrict__ wvbar,
                                               float* __restrict__ bvbar) {
    int idx = blockIdx.x * 256 + threadIdx.x;   // 16 blocks -> 4096, 4 cols each
    int d = idx >> 6;
    int c0 = (idx & 63) * 4;
    const float4* W4 = (const float4*)Wv;
    float4 w0 = W4[((d) * 256 + c0) >> 2];
    float4 w1 = W4[((64 + d) * 256 + c0) >> 2];
    float4 w2 = W4[((128 + d) * 256 + c0) >> 2];
    float4 w3 = W4[((192 + d) * 256 + c0) >> 2];
    ushort4 s;
    s.x = f2bf(0.25f * (w0.x + w1.x + w2.x + w3.x));
    s.y = f2bf(0.25f * (w0.y + w1.y + w2.y + w3.y));
    s.z = f2bf(0.25f * (w0.z + w1.z + w2.z + w3.z));
    s.w = f2bf(0.25f * (w0.w + w1.w + w2.w + w3.w));
    int ks = c0 >> 5;
    int q  = (c0 >> 3) & 3;
    int j0 = c0 & 7;                            // 0 or 4 -> ushort4 stays contiguous
    int nf = d >> 4;
    int ln = d & 15;
    int base = ((ks * 4 + nf) * 64 + q * 16 + ln) * 8 + j0;
    *(ushort4*)&wvbar[base] = s;
    if (blockIdx.x == 0 && threadIdx.x < 64) {
        int t = threadIdx.x;
        bvbar[t] = 0.25f * (bv[t] + bv[64 + t] + bv[128 + t] + bv[192 + t]);
    }
}

// ---------------- edge partition into 512 col-range buckets ----------------
// entry = { row<<16 | bf16(w), lcol };  block-contiguous runs per bucket region.
__global__ __launch_bounds__(256) void k_part(const int* __restrict__ ei,
                                              const float* __restrict__ ew,
                                              int* __restrict__ gcur,
                                              uint2* __restrict__ bkt)
{
    __shared__ int hist[NBUK];
    __shared__ int cur[NBUK];
    const int t = threadIdx.x;
    const int e0 = blockIdx.x * PCHUNK;
    hist[t] = 0; hist[t + 256] = 0;
    __syncthreads();
    #pragma unroll
    for (int k = 0; k < PCHUNK / 256; ++k) {
        int e = e0 + k * 256 + t;
        if (e < N_EDGES) {
            int c = ei[N_EDGES + e];
            atomicAdd(&hist[c / BWID], 1);
        }
    }
    __syncthreads();
    {
        int b = t;
        if (hist[b]) cur[b] = b * BCAP + atomicAdd(&gcur[b], hist[b]);
        b = t + 256;
        if (hist[b]) cur[b] = b * BCAP + atomicAdd(&gcur[b], hist[b]);
    }
    __syncthreads();
    #pragma unroll
    for (int k = 0; k < PCHUNK / 256; ++k) {
        int e = e0 + k * 256 + t;
        if (e < N_EDGES) {
            int c = ei[N_EDGES + e];
            int b = c / BWID;
            int row = ei[e];
            float w = ew[e];
            int slot = atomicAdd(&cur[b], 1);
            if (slot < (b + 1) * BCAP) {
                uint2 en;
                en.x = ((unsigned int)row << 16) | (unsigned int)f2bf(w);
                en.y = (unsigned int)(c - b * BWID);
                bkt[slot] = en;
            }
        }
    }
}

// ---------------- per-bucket: deg + off (into padded layout) + in-bucket sort --
__global__ __launch_bounds__(256) void k_bucket(const int* __restrict__ gcur,
                                                const uint2* __restrict__ bkt,
                                                int* __restrict__ deg,
                                                int* __restrict__ off,
                                                unsigned int* __restrict__ srt)
{
    __shared__ int hist[128];       // >= BWID
    __shared__ int lcur[128];
    const int t = threadIdx.x;
    const int b = blockIdx.x;
    if (t < 128) hist[t] = 0;
    __syncthreads();
    const int cnt = min(gcur[b], BCAP);
    const uint2* base = bkt + (size_t)b * BCAP;
    for (int i = t; i < cnt; i += 256)
        atomicAdd(&hist[base[i].y], 1);
    __syncthreads();
    // exclusive scan over 128 — ALL threads execute every barrier (t>=128 idle)
    const int v = (t < 128) ? hist[t] : 0;
    #pragma unroll
    for (int d = 1; d < 128; d <<= 1) {
        int u = (t >= d && t < 128) ? hist[t - d] : 0;
        __syncthreads();
        if (t >= d && t < 128) hist[t] += u;
        __syncthreads();
    }
    if (t < 128) {
        int excl = hist[t] - v;
        lcur[t] = excl;
        if (t < BWID) {
            int col = b * BWID + t;
            if (col < N_NODES) {
                deg[col] = v;
                off[col] = b * BCAP + excl;
            }
        }
    }
    __syncthreads();
    unsigned int* sb = srt + (size_t)b * BCAP;
    for (int i = t; i < cnt; i += 256) {
        uint2 en = base[i];
        int pos = atomicAdd(&lcur[en.y], 1);
        sb[pos] = en.x;             // row<<16 | bf16(w)
    }
}

// ---------------- vbar GEMM: barrier-free, per-wave K-halved staging ----------
// vbarh[n,d] = bf16( (sum_c Xs[n,c]*Wvbar[d,c] + bvbar[d]) * rsqrt(deg[n]) )
// vsumr[rep][d] += sum_n acc (pre-bias, UNSCALED) for the attention constant.
// Wave w stages AND reads only rows w*16..w*16+15 -> no cross-wave dependency,
// no __syncthreads. K staged in two 128-col halves into the SAME 32 KB buffer
// (guarded by lgkmcnt(0) before restage). 32 KB LDS -> 5 blocks/CU, whole grid
// resident. Global src pre-XOR-swizzled so frag ds_read_b128 is conflict-free.
__global__ __launch_bounds__(256) void k_vbar(
    const float* __restrict__ Xs, const unsigned short* __restrict__ wvbar,
    const float* __restrict__ bvbar, const int* __restrict__ deg,
    unsigned short* __restrict__ vbarh, float* __restrict__ vsumr)
{
    __shared__ float lX[64 * 128];    // 32 KB: one K-half (128 cols), reused
    const int t = threadIdx.x;
    const int w = t >> 6;
    const int l = t & 63;
    const int ln = l & 15;
    const int q = l >> 4;
    const int n0 = blockIdx.x * 64;

    const char* Xc = (const char*)Xs;
    const bf16x8* Wf = (const bf16x8*)wvbar;        // frag-swizzled, L2-hot
    const unsigned int swzl = ((unsigned int)(ln & 7)) << 4;  // row=w*16+ln, w*16%8==0
    const char* lrow = (const char*)&lX[(w * 16 + ln) * 128];

    f32x4 acc[4];
    #pragma unroll
    for (int nf = 0; nf < 4; ++nf) acc[nf] = (f32x4){0.f, 0.f, 0.f, 0.f};

    #pragma unroll
    for (int h = 0; h < 2; ++h) {
        // --- stage half h: 8 calls/wave, each = 2 rows x 512 B (per-lane src) ---
        #pragma unroll
        for (int i = 0; i < 8; ++i) {
            int r = w * 16 + i * 2 + (l >> 5);          // per-lane row in tile
            int g = n0 + r;
            int gc = (g < N_NODES) ? g : 0;             // clamp OOB, masked later
            unsigned int off = ((unsigned int)((l & 31) * 16))
                             ^ (((unsigned int)(r & 7)) << 4);
            const void* src = Xc + (size_t)gc * 1024 + (unsigned int)(h * 512) + off;
            gld_lds16(src, &lX[(w * 16 + i * 2) * 128]);  // wave-uniform dest base
        }
        asm volatile("s_waitcnt vmcnt(0)" ::: "memory");  // per-wave drain only
        __builtin_amdgcn_sched_barrier(0);

        // --- compute this half: ks = h*4 + ks2 ---
        #pragma unroll
        for (int ks2 = 0; ks2 < 4; ++ks2) {
            unsigned int c0 = (unsigned int)(ks2 * 128 + q * 32);
            float4 xa = *(const float4*)(lrow + (c0 ^ swzl));
            float4 xb = *(const float4*)(lrow + ((c0 + 16u) ^ swzl));
            bf16x8 A;
            A[0] = (__bf16)xa.x; A[1] = (__bf16)xa.y;
            A[2] = (__bf16)xa.z; A[3] = (__bf16)xa.w;
            A[4] = (__bf16)xb.x; A[5] = (__bf16)xb.y;
            A[6] = (__bf16)xb.z; A[7] = (__bf16)xb.w;
            int ks = h * 4 + ks2;
            #pragma unroll
            for (int nf = 0; nf < 4; ++nf) {
                bf16x8 b = Wf[(ks * 4 + nf) * 64 + l];
                acc[nf] = __builtin_amdgcn_mfma_f32_16x16x32_bf16(A, b, acc[nf], 0, 0, 0);
            }
        }
        if (h == 0) {
            // all h0 LDS reads must retire before h1 overwrites the buffer
            asm volatile("s_waitcnt lgkmcnt(0)" ::: "memory");
            __builtin_amdgcn_sched_barrier(0);
        }
    }

    // epilogue: D[m = q*4+r4][n = ln]; write bf16 vbar pre-scaled by rsqrt(deg)
    float bvb[4];
    #pragma unroll
    for (int nf = 0; nf < 4; ++nf) bvb[nf] = bvbar[nf * 16 + ln];
    float psum[4] = {0.f, 0.f, 0.f, 0.f};
    #pragma unroll
    for (int r4 = 0; r4 < 4; ++r4) {
        int g = n0 + w * 16 + q * 4 + r4;
        bool ok = g < N_NODES;
        float sc = 0.f;
        if (ok) {
            float dg = (float)deg[g];
            sc = (dg > 0.f) ? __frsqrt_rn(dg) : 0.f;
        }
        #pragma unroll
        for (int nf = 0; nf < 4; ++nf) {
            if (ok) {
                vbarh[g * 64 + nf * 16 + ln] = f2bf((acc[nf][r4] + bvb[nf]) * sc);
                psum[nf] += acc[nf][r4];   // OOB rows excluded
            }
        }
    }
    // reduce over q-groups in-register (no LDS, no barrier), then 1 atomic/col
    #pragma unroll
    for (int nf = 0; nf < 4; ++nf) {
        float v = psum[nf];
        v += __shfl_xor(v, 16, 64);
        v += __shfl_xor(v, 32, 64);
        psum[nf] = v;
    }
    if (l < 16) {
        int rep = (blockIdx.x * 4 + w) & (NVS - 1);
        #pragma unroll
        for (int nf = 0; nf < 4; ++nf)
            atomicAdd(&vsumr[rep * 64 + nf * 16 + ln], psum[nf]);
    }
}

// ---------------- GCN gather: one wave per node, lane = d-channel ----------------
// out[n,d] = aconst[d] + rsqrt(deg[n]) * sum_e w_e * vbarh[row_e, d]
__global__ __launch_bounds__(256) void k_gather(
    const int* __restrict__ off, const int* __restrict__ deg,
    const unsigned int* __restrict__ srt, const unsigned short* __restrict__ vbarh,
    const float* __restrict__ vsumr, const float* __restrict__ bvbar,
    float* __restrict__ out)
{
    const int t = threadIdx.x;
    const int lane = t & 63;
    const int n = blockIdx.x * 4 + (t >> 6);          // grid: 12544 blocks -> 50176
    if (n >= N_NODES) return;                          // whole wave exits together
    const int e0 = off[n];
    const int dc = deg[n];
    const int e1 = e0 + dc;
    float acc = 0.f;
    int e = e0;
    for (; e + 3 < e1; e += 4) {
        unsigned int p0 = srt[e];
        unsigned int p1 = srt[e + 1];
        unsigned int p2 = srt[e + 2];
        unsigned int p3 = srt[e + 3];
        float a0 = __uint_as_float(p0 << 16) * bf2f(vbarh[(p0 >> 16) * 64 + lane]);
        float a1 = __uint_as_float(p1 << 16) * bf2f(vbarh[(p1 >> 16) * 64 + lane]);
        float a2 = __uint_as_float(p2 << 16) * bf2f(vbarh[(p2 >> 16) * 64 + lane]);
        float a3 = __uint_as_float(p3 << 16) * bf2f(vbarh[(p3 >> 16) * 64 + lane]);
        acc += (a0 + a1) + (a2 + a3);
    }
    for (; e < e1; ++e) {
        unsigned int p = srt[e];
        acc += __uint_as_float(p << 16) * bf2f(vbarh[(p >> 16) * 64 + lane]);
    }
    float dcf = (float)dc;
    float scn = (dcf > 0.f) ? __frsqrt_rn(dcf) : 0.f;
    float vs = 0.f;
    #pragma unroll
    for (int i = 0; i < NVS; ++i) vs += vsumr[i * 64 + lane];
    float aconst = vs * (1.0f / (float)N_NODES) + bvbar[lane];
    out[n * 64 + lane] = acc * scn + aconst;
}

extern "C" void kernel_launch(void* const* d_in, const int* in_sizes, int n_in,
                              void* d_out, int out_size, void* d_ws, size_t ws_size,
                              hipStream_t stream)
{
    const float* Xs = (const float*)d_in[1];   // source_input [N,256]
    const float* Wv = (const float*)d_in[6];   // Wv_w [256,256]
    const float* bv = (const float*)d_in[7];   // Wv_b [256]
    const int*   ei = (const int*)d_in[8];     // edge_index [2,E]
    const float* ew = (const float*)d_in[9];   // edge_weight [E]
    float* out = (float*)d_out;                // [N,64]

    unsigned short* vbarh = (unsigned short*)d_ws;               // 3.2M bf16 (6.4 MB)
    uint2* bkt  = (uint2*)(vbarh + (size_t)N_NODES * 64);        // 512*2048*8 = 8.39 MB
    unsigned int* srt = (unsigned int*)(bkt + (size_t)NBUK * BCAP); // 4.19 MB
    unsigned short* wvbar = (unsigned short*)(srt + (size_t)NBUK * BCAP); // 32 KB
    float* bvbar   = (float*)(wvbar + 16384);                    // 64
    float* vsumr   = bvbar + 64;                                 // 32 x 64 replicas
    int*   gcur    = (int*)(vsumr + NVS * 64);                   // 512
    int*   deg     = gcur + NBUK;                                // 50,000
    int*   off     = deg + N_NODES;                              // 50,000

    // zero vsum replicas + gcur (adjacent); rest fully written by kernels
    hipMemsetAsync(vsumr, 0, (size_t)(NVS * 64 + NBUK) * 4, stream);
    k_wprep<<<16, 256, 0, stream>>>(Wv, bv, wvbar, bvbar);
    k_part<<<PBLK, 256, 0, stream>>>(ei, ew, gcur, bkt);
    k_bucket<<<NBUK, 256, 0, stream>>>(gcur, bkt, deg, off, srt);
    k_vbar<<<(N_NODES + 63) / 64, 256, 0, stream>>>(Xs, wvbar, bvbar, deg, vbarh, vsumr);
    k_gather<<<(NBUK * BWID) / 4, 256, 0, stream>>>(off, deg, srt, vbarh, vsumr, bvbar, out);
}

// Round 5
// 210.471 us; speedup vs baseline: 1.0921x; 1.0224x over previous
//
#include <hip/hip_runtime.h>
#include <hip/hip_bf16.h>

#define N_NODES 50000
#define N_EDGES 800000
#define NBUK 512            // col-range buckets
#define BWID 98             // cols per bucket: 512*98 = 50176 >= N
#define BCAP 2048           // entries cap/bucket (mean 1562, +12 sigma)
#define PCHUNK 4096         // edges per partition block (bigger -> longer dst runs)
#define PBLK 196            // ceil(800000/4096)
#define NVS 32              // vsumcol replicas (atomic de-contention)

typedef __bf16 bf16x8 __attribute__((ext_vector_type(8)));
typedef float f32x4 __attribute__((ext_vector_type(4)));

__device__ __forceinline__ unsigned short f2bf(float f) {
    unsigned int u = __builtin_bit_cast(unsigned int, f);
    u += 0x7fffu + ((u >> 16) & 1u);   // round-to-nearest-even
    return (unsigned short)(u >> 16);
}
__device__ __forceinline__ float bf2f(unsigned short s) {
    return __uint_as_float((unsigned int)s << 16);
}

// async 16B global->LDS (no VGPR result; LDS dest = wave-uniform base + lane*16)
__device__ __forceinline__ void gld_lds16(const void* g, void* lds) {
    __builtin_amdgcn_global_load_lds(
        (const __attribute__((address_space(1))) unsigned int*)g,
        (__attribute__((address_space(3))) unsigned int*)lds, 16, 0, 0);
}

// ---------------- Wvbar prep: head-averaged Wv -> bf16, MFMA-frag-swizzled ----
// element (d,c) -> frag ks=c>>5, nf=d>>4, lane = ((c>>3)&3)*16 + (d&15), j=c&7
// stored at ((ks*4+nf)*64 + lane)*8 + j  (so a wave's b-frag load is 1 KB coalesced)
__global__ __launch_bounds__(256) void k_wprep(const float* __restrict__ Wv,
                                               const float* __restrict__ bv,
                                               unsigned short* __restrict__ wvbar,
                                               float* __restrict__ bvbar) {
    int idx = blockIdx.x * 256 + threadIdx.x;   // 16 blocks -> 4096, 4 cols each
    int d = idx >> 6;
    int c0 = (idx & 63) * 4;
    const float4* W4 = (const float4*)Wv;
    float4 w0 = W4[((d) * 256 + c0) >> 2];
    float4 w1 = W4[((64 + d) * 256 + c0) >> 2];
    float4 w2 = W4[((128 + d) * 256 + c0) >> 2];
    float4 w3 = W4[((192 + d) * 256 + c0) >> 2];
    ushort4 s;
    s.x = f2bf(0.25f * (w0.x + w1.x + w2.x + w3.x));
    s.y = f2bf(0.25f * (w0.y + w1.y + w2.y + w3.y));
    s.z = f2bf(0.25f * (w0.z + w1.z + w2.z + w3.z));
    s.w = f2bf(0.25f * (w0.w + w1.w + w2.w + w3.w));
    int ks = c0 >> 5;
    int q  = (c0 >> 3) & 3;
    int j0 = c0 & 7;                            // 0 or 4 -> ushort4 stays contiguous
    int nf = d >> 4;
    int ln = d & 15;
    int base = ((ks * 4 + nf) * 64 + q * 16 + ln) * 8 + j0;
    *(ushort4*)&wvbar[base] = s;
    if (blockIdx.x == 0 && threadIdx.x < 64) {
        int t = threadIdx.x;
        bvbar[t] = 0.25f * (bv[t] + bv[64 + t] + bv[128 + t] + bv[192 + t]);
    }
}

// ---------------- edge partition into 512 col-range buckets ----------------
// LDS counting-sort per 4096-edge chunk; write-out is bucket-grouped so global
// writes form ~8-entry (64 B) runs per bucket instead of fully scattered 8 B.
__global__ __launch_bounds__(256) void k_part(const int* __restrict__ ei,
                                              const float* __restrict__ ew,
                                              int* __restrict__ gcur,
                                              uint2* __restrict__ bkt)
{
    __shared__ int hist[NBUK];              // 2 KB
    __shared__ int s2[256];                 // 1 KB (scan of bin-pairs)
    __shared__ int lstart[NBUK];            // 2 KB
    __shared__ int lcur[NBUK];              // 2 KB
    __shared__ int gbase[NBUK];             // 2 KB
    __shared__ uint2 lent[PCHUNK];          // 32 KB sorted entries
    __shared__ unsigned int ldst[PCHUNK];   // 16 KB global dst per entry
    const int t = threadIdx.x;
    const int e0 = blockIdx.x * PCHUNK;
    const int cnt = min(N_EDGES - e0, PCHUNK);

    hist[t] = 0; hist[t + 256] = 0;
    __syncthreads();
    #pragma unroll
    for (int k = 0; k < PCHUNK / 256; ++k) {
        int e = e0 + k * 256 + t;
        if (e < N_EDGES) atomicAdd(&hist[ei[N_EDGES + e] / BWID], 1);
    }
    __syncthreads();
    // reserve global runs (one atomic per non-empty bucket)
    {
        int b = t;
        if (hist[b]) gbase[b] = b * BCAP + atomicAdd(&gcur[b], hist[b]);
        b = t + 256;
        if (hist[b]) gbase[b] = b * BCAP + atomicAdd(&gcur[b], hist[b]);
    }
    // exclusive scan over 512 bins: pair-sum (256) -> inclusive ladder -> expand
    s2[t] = hist[2 * t] + hist[2 * t + 1];
    __syncthreads();
    #pragma unroll
    for (int d = 1; d < 256; d <<= 1) {
        int u = (t >= d) ? s2[t - d] : 0;
        __syncthreads();
        s2[t] += u;
        __syncthreads();
    }
    {
        int b0 = (t > 0) ? s2[t - 1] : 0;
        lstart[2 * t] = b0;
        lstart[2 * t + 1] = b0 + hist[2 * t];
        lcur[2 * t] = b0;
        lcur[2 * t + 1] = b0 + hist[2 * t];
    }
    __syncthreads();
    // scatter into LDS, bucket-sorted; record global destination
    #pragma unroll
    for (int k = 0; k < PCHUNK / 256; ++k) {
        int e = e0 + k * 256 + t;
        if (e < N_EDGES) {
            int c = ei[N_EDGES + e];
            int b = c / BWID;
            int lp = atomicAdd(&lcur[b], 1);
            uint2 en;
            en.x = ((unsigned int)ei[e] << 16) | (unsigned int)f2bf(ew[e]);
            en.y = (unsigned int)(c - b * BWID);
            lent[lp] = en;
            unsigned int gd = (unsigned int)(gbase[b] + (lp - lstart[b]));
            ldst[lp] = (gd < (unsigned int)((b + 1) * BCAP)) ? gd : 0xFFFFFFFFu;
        }
    }
    __syncthreads();
    // coalesced write-out: consecutive threads -> consecutive dsts within runs
    for (int j = t; j < cnt; j += 256) {
        unsigned int gd = ldst[j];
        if (gd != 0xFFFFFFFFu) bkt[gd] = lent[j];
    }
}

// ---------------- per-bucket: deg + off + in-bucket sort (LDS-staged) ---------
__global__ __launch_bounds__(256) void k_bucket(const int* __restrict__ gcur,
                                                const uint2* __restrict__ bkt,
                                                int* __restrict__ deg,
                                                int* __restrict__ off,
                                                unsigned int* __restrict__ srt)
{
    __shared__ int hist[128];       // >= BWID
    __shared__ int lcur[128];
    __shared__ unsigned int stg[BCAP];   // 8 KB: sorted entries staged in LDS
    const int t = threadIdx.x;
    const int b = blockIdx.x;
    if (t < 128) hist[t] = 0;
    __syncthreads();
    const int cnt = min(gcur[b], BCAP);
    const uint2* base = bkt + (size_t)b * BCAP;
    for (int i = t; i < cnt; i += 256)
        atomicAdd(&hist[base[i].y], 1);
    __syncthreads();
    // exclusive scan over 128 — ALL threads execute every barrier (t>=128 idle)
    const int v = (t < 128) ? hist[t] : 0;
    #pragma unroll
    for (int d = 1; d < 128; d <<= 1) {
        int u = (t >= d && t < 128) ? hist[t - d] : 0;
        __syncthreads();
        if (t >= d && t < 128) hist[t] += u;
        __syncthreads();
    }
    if (t < 128) {
        int excl = hist[t] - v;
        lcur[t] = excl;
        if (t < BWID) {
            int col = b * BWID + t;
            if (col < N_NODES) {
                deg[col] = v;
                off[col] = b * BCAP + excl;
            }
        }
    }
    __syncthreads();
    for (int i = t; i < cnt; i += 256) {
        uint2 en = base[i];
        int pos = atomicAdd(&lcur[en.y], 1);
        stg[pos] = en.x;            // row<<16 | bf16(w), sorted by lcol in LDS
    }
    __syncthreads();
    unsigned int* sb = srt + (size_t)b * BCAP;
    for (int i = t; i < cnt; i += 256) sb[i] = stg[i];   // coalesced
}

// ---------------- vbar GEMM: barrier-free, per-wave K-halved staging ----------
// vbarh[n,d] = bf16( (sum_c Xs[n,c]*Wvbar[d,c] + bvbar[d]) * rsqrt(deg[n]) )
// vsumr[rep][d] += sum_n acc (pre-bias, UNSCALED) for the attention constant.
__global__ __launch_bounds__(256) void k_vbar(
    const float* __restrict__ Xs, const unsigned short* __restrict__ wvbar,
    const float* __restrict__ bvbar, const int* __restrict__ deg,
    unsigned short* __restrict__ vbarh, float* __restrict__ vsumr)
{
    __shared__ float lX[64 * 128];    // 32 KB: one K-half (128 cols), reused
    const int t = threadIdx.x;
    const int w = t >> 6;
    const int l = t & 63;
    const int ln = l & 15;
    const int q = l >> 4;
    const int n0 = blockIdx.x * 64;

    const char* Xc = (const char*)Xs;
    const bf16x8* Wf = (const bf16x8*)wvbar;        // frag-swizzled, L2-hot
    const unsigned int swzl = ((unsigned int)(ln & 7)) << 4;  // row=w*16+ln, w*16%8==0
    const char* lrow = (const char*)&lX[(w * 16 + ln) * 128];

    f32x4 acc[4];
    #pragma unroll
    for (int nf = 0; nf < 4; ++nf) acc[nf] = (f32x4){0.f, 0.f, 0.f, 0.f};

    #pragma unroll
    for (int h = 0; h < 2; ++h) {
        // --- stage half h: 8 calls/wave, each = 2 rows x 512 B (per-lane src) ---
        #pragma unroll
        for (int i = 0; i < 8; ++i) {
            int r = w * 16 + i * 2 + (l >> 5);          // per-lane row in tile
            int g = n0 + r;
            int gc = (g < N_NODES) ? g : 0;             // clamp OOB, masked later
            unsigned int off = ((unsigned int)((l & 31) * 16))
                             ^ (((unsigned int)(r & 7)) << 4);
            const void* src = Xc + (size_t)gc * 1024 + (unsigned int)(h * 512) + off;
            gld_lds16(src, &lX[(w * 16 + i * 2) * 128]);  // wave-uniform dest base
        }
        asm volatile("s_waitcnt vmcnt(0)" ::: "memory");  // per-wave drain only
        __builtin_amdgcn_sched_barrier(0);

        // --- compute this half: ks = h*4 + ks2 ---
        #pragma unroll
        for (int ks2 = 0; ks2 < 4; ++ks2) {
            unsigned int c0 = (unsigned int)(ks2 * 128 + q * 32);
            float4 xa = *(const float4*)(lrow + (c0 ^ swzl));
            float4 xb = *(const float4*)(lrow + ((c0 + 16u) ^ swzl));
            bf16x8 A;
            A[0] = (__bf16)xa.x; A[1] = (__bf16)xa.y;
            A[2] = (__bf16)xa.z; A[3] = (__bf16)xa.w;
            A[4] = (__bf16)xb.x; A[5] = (__bf16)xb.y;
            A[6] = (__bf16)xb.z; A[7] = (__bf16)xb.w;
            int ks = h * 4 + ks2;
            #pragma unroll
            for (int nf = 0; nf < 4; ++nf) {
                bf16x8 b = Wf[(ks * 4 + nf) * 64 + l];
                acc[nf] = __builtin_amdgcn_mfma_f32_16x16x32_bf16(A, b, acc[nf], 0, 0, 0);
            }
        }
        if (h == 0) {
            // all h0 LDS reads must retire before h1 overwrites the buffer
            asm volatile("s_waitcnt lgkmcnt(0)" ::: "memory");
            __builtin_amdgcn_sched_barrier(0);
        }
    }

    // epilogue: D[m = q*4+r4][n = ln]; write bf16 vbar pre-scaled by rsqrt(deg)
    float bvb[4];
    #pragma unroll
    for (int nf = 0; nf < 4; ++nf) bvb[nf] = bvbar[nf * 16 + ln];
    float psum[4] = {0.f, 0.f, 0.f, 0.f};
    #pragma unroll
    for (int r4 = 0; r4 < 4; ++r4) {
        int g = n0 + w * 16 + q * 4 + r4;
        bool ok = g < N_NODES;
        float sc = 0.f;
        if (ok) {
            float dg = (float)deg[g];
            sc = (dg > 0.f) ? __frsqrt_rn(dg) : 0.f;
        }
        #pragma unroll
        for (int nf = 0; nf < 4; ++nf) {
            if (ok) {
                vbarh[g * 64 + nf * 16 + ln] = f2bf((acc[nf][r4] + bvb[nf]) * sc);
                psum[nf] += acc[nf][r4];   // OOB rows excluded
            }
        }
    }
    // reduce over q-groups in-register (no LDS, no barrier), then 1 atomic/col
    #pragma unroll
    for (int nf = 0; nf < 4; ++nf) {
        float v = psum[nf];
        v += __shfl_xor(v, 16, 64);
        v += __shfl_xor(v, 32, 64);
        psum[nf] = v;
    }
    if (l < 16) {
        int rep = (blockIdx.x * 4 + w) & (NVS - 1);
        #pragma unroll
        for (int nf = 0; nf < 4; ++nf)
            atomicAdd(&vsumr[rep * 64 + nf * 16 + ln], psum[nf]);
    }
}

// ---------------- GCN gather: one wave per node, lane = d-channel ----------------
// out[n,d] = aconst[d] + rsqrt(deg[n]) * sum_e w_e * vbarh[row_e, d]
__global__ __launch_bounds__(256) void k_gather(
    const int* __restrict__ off, const int* __restrict__ deg,
    const unsigned int* __restrict__ srt, const unsigned short* __restrict__ vbarh,
    const float* __restrict__ vsumr, const float* __restrict__ bvbar,
    float* __restrict__ out)
{
    const int t = threadIdx.x;
    const int lane = t & 63;
    const int n = blockIdx.x * 4 + (t >> 6);          // grid: 12544 blocks -> 50176
    if (n >= N_NODES) return;                          // whole wave exits together
    const int e0 = off[n];
    const int dc = deg[n];
    const int e1 = e0 + dc;
    float acc = 0.f;
    int e = e0;
    for (; e + 3 < e1; e += 4) {
        unsigned int p0 = srt[e];
        unsigned int p1 = srt[e + 1];
        unsigned int p2 = srt[e + 2];
        unsigned int p3 = srt[e + 3];
        float a0 = __uint_as_float(p0 << 16) * bf2f(vbarh[(p0 >> 16) * 64 + lane]);
        float a1 = __uint_as_float(p1 << 16) * bf2f(vbarh[(p1 >> 16) * 64 + lane]);
        float a2 = __uint_as_float(p2 << 16) * bf2f(vbarh[(p2 >> 16) * 64 + lane]);
        float a3 = __uint_as_float(p3 << 16) * bf2f(vbarh[(p3 >> 16) * 64 + lane]);
        acc += (a0 + a1) + (a2 + a3);
    }
    for (; e < e1; ++e) {
        unsigned int p = srt[e];
        acc += __uint_as_float(p << 16) * bf2f(vbarh[(p >> 16) * 64 + lane]);
    }
    float dcf = (float)dc;
    float scn = (dcf > 0.f) ? __frsqrt_rn(dcf) : 0.f;
    float vs = 0.f;
    #pragma unroll
    for (int i = 0; i < NVS; ++i) vs += vsumr[i * 64 + lane];
    float aconst = vs * (1.0f / (float)N_NODES) + bvbar[lane];
    out[n * 64 + lane] = acc * scn + aconst;
}

extern "C" void kernel_launch(void* const* d_in, const int* in_sizes, int n_in,
                              void* d_out, int out_size, void* d_ws, size_t ws_size,
                              hipStream_t stream)
{
    const float* Xs = (const float*)d_in[1];   // source_input [N,256]
    const float* Wv = (const float*)d_in[6];   // Wv_w [256,256]
    const float* bv = (const float*)d_in[7];   // Wv_b [256]
    const int*   ei = (const int*)d_in[8];     // edge_index [2,E]
    const float* ew = (const float*)d_in[9];   // edge_weight [E]
    float* out = (float*)d_out;                // [N,64]

    unsigned short* vbarh = (unsigned short*)d_ws;               // 3.2M bf16 (6.4 MB)
    uint2* bkt  = (uint2*)(vbarh + (size_t)N_NODES * 64);        // 512*2048*8 = 8.39 MB
    unsigned int* srt = (unsigned int*)(bkt + (size_t)NBUK * BCAP); // 4.19 MB
    unsigned short* wvbar = (unsigned short*)(srt + (size_t)NBUK * BCAP); // 32 KB
    float* bvbar   = (float*)(wvbar + 16384);                    // 64
    float* vsumr   = bvbar + 64;                                 // 32 x 64 replicas
    int*   gcur    = (int*)(vsumr + NVS * 64);                   // 512
    int*   deg     = gcur + NBUK;                                // 50,000
    int*   off     = deg + N_NODES;                              // 50,000

    // zero vsum replicas + gcur (adjacent); rest fully written by kernels
    hipMemsetAsync(vsumr, 0, (size_t)(NVS * 64 + NBUK) * 4, stream);
    k_wprep<<<16, 256, 0, stream>>>(Wv, bv, wvbar, bvbar);
    k_part<<<PBLK, 256, 0, stream>>>(ei, ew, gcur, bkt);
    k_bucket<<<NBUK, 256, 0, stream>>>(gcur, bkt, deg, off, srt);
    k_vbar<<<(N_NODES + 63) / 64, 256, 0, stream>>>(Xs, wvbar, bvbar, deg, vbarh, vsumr);
    k_gather<<<(NBUK * BWID) / 4, 256, 0, stream>>>(off, deg, srt, vbarh, vsumr, bvbar, out);
}

// Round 6
// 197.865 us; speedup vs baseline: 1.1617x; 1.0637x over previous
//
#include <hip/hip_runtime.h>
#include <hip/hip_bf16.h>

#define N_NODES 50000
#define N_EDGES 800000
#define NBUK 512            // col-range buckets
#define BWID 98             // cols per bucket: 512*98 = 50176 >= N
#define BCAP 2048           // entries cap/bucket (mean 1562, +12 sigma)
#define PCHUNK 2048         // edges per partition block (38 KB LDS -> 4 blocks/CU)
#define PBLK 391            // ceil(800000/2048)
#define NVS 32              // vsumcol replicas (atomic de-contention)

typedef __bf16 bf16x8 __attribute__((ext_vector_type(8)));
typedef float f32x4 __attribute__((ext_vector_type(4)));

__device__ __forceinline__ unsigned short f2bf(float f) {
    unsigned int u = __builtin_bit_cast(unsigned int, f);
    u += 0x7fffu + ((u >> 16) & 1u);   // round-to-nearest-even
    return (unsigned short)(u >> 16);
}
__device__ __forceinline__ float bf2f(unsigned short s) {
    return __uint_as_float((unsigned int)s << 16);
}

// async 16B global->LDS (no VGPR result; LDS dest = wave-uniform base + lane*16)
__device__ __forceinline__ void gld_lds16(const void* g, void* lds) {
    __builtin_amdgcn_global_load_lds(
        (const __attribute__((address_space(1))) unsigned int*)g,
        (__attribute__((address_space(3))) unsigned int*)lds, 16, 0, 0);
}

// ---------------- Wvbar prep + workspace zeroing (replaces hipMemsetAsync) ----
// element (d,c) -> frag ks=c>>5, nf=d>>4, lane = ((c>>3)&3)*16 + (d&15), j=c&7
// stored at ((ks*4+nf)*64 + lane)*8 + j  (so a wave's b-frag load is 1 KB coalesced)
__global__ __launch_bounds__(256) void k_wprep(const float* __restrict__ Wv,
                                               const float* __restrict__ bv,
                                               unsigned short* __restrict__ wvbar,
                                               float* __restrict__ bvbar,
                                               int* __restrict__ gcur,
                                               float* __restrict__ vsumr) {
    int idx = blockIdx.x * 256 + threadIdx.x;   // 16 blocks -> 4096, 4 cols each
    int d = idx >> 6;
    int c0 = (idx & 63) * 4;
    const float4* W4 = (const float4*)Wv;
    float4 w0 = W4[((d) * 256 + c0) >> 2];
    float4 w1 = W4[((64 + d) * 256 + c0) >> 2];
    float4 w2 = W4[((128 + d) * 256 + c0) >> 2];
    float4 w3 = W4[((192 + d) * 256 + c0) >> 2];
    ushort4 s;
    s.x = f2bf(0.25f * (w0.x + w1.x + w2.x + w3.x));
    s.y = f2bf(0.25f * (w0.y + w1.y + w2.y + w3.y));
    s.z = f2bf(0.25f * (w0.z + w1.z + w2.z + w3.z));
    s.w = f2bf(0.25f * (w0.w + w1.w + w2.w + w3.w));
    int ks = c0 >> 5;
    int q  = (c0 >> 3) & 3;
    int j0 = c0 & 7;                            // 0 or 4 -> ushort4 stays contiguous
    int nf = d >> 4;
    int ln = d & 15;
    int base = ((ks * 4 + nf) * 64 + q * 16 + ln) * 8 + j0;
    *(ushort4*)&wvbar[base] = s;
    if (blockIdx.x == 0 && threadIdx.x < 64) {
        int t = threadIdx.x;
        bvbar[t] = 0.25f * (bv[t] + bv[64 + t] + bv[128 + t] + bv[192 + t]);
    }
    // zero gcur + vsumr before k_part / k_vbar (kernel boundary orders this)
    if (blockIdx.x == 1) {
        for (int i = threadIdx.x; i < NBUK; i += 256) gcur[i] = 0;
    }
    if (blockIdx.x == 2) {
        for (int i = threadIdx.x; i < NVS * 64; i += 256) vsumr[i] = 0.f;
    }
}

// ---------------- edge partition into 512 col-range buckets ----------------
// LDS counting-sort per 2048-edge chunk (38 KB LDS -> 4 blocks/CU); col cached
// in LDS as ushort so ei's col row is read once; write-out is bucket-grouped so
// global writes form 64 B runs per bucket instead of fully scattered 8 B.
__global__ __launch_bounds__(256) void k_part(const int* __restrict__ ei,
                                              const float* __restrict__ ew,
                                              int* __restrict__ gcur,
                                              uint2* __restrict__ bkt)
{
    __shared__ int hist[NBUK];              // 2 KB
    __shared__ int s2[256];                 // 1 KB (scan of bin-pairs)
    __shared__ int lstart[NBUK];            // 2 KB
    __shared__ int lcur[NBUK];              // 2 KB
    __shared__ int gbase[NBUK];             // 2 KB
    __shared__ unsigned short scol[PCHUNK]; // 4 KB cached col per edge
    __shared__ uint2 lent[PCHUNK];          // 16 KB sorted entries
    __shared__ unsigned int ldst[PCHUNK];   // 8 KB global dst per entry
    const int t = threadIdx.x;
    const int e0 = blockIdx.x * PCHUNK;
    const int cnt = min(N_EDGES - e0, PCHUNK);

    hist[t] = 0; hist[t + 256] = 0;
    __syncthreads();
    #pragma unroll
    for (int k = 0; k < PCHUNK / 256; ++k) {
        int idx = k * 256 + t;
        int e = e0 + idx;
        if (e < N_EDGES) {
            int c = ei[N_EDGES + e];
            scol[idx] = (unsigned short)c;
            atomicAdd(&hist[c / BWID], 1);
        }
    }
    __syncthreads();
    // reserve global runs (one atomic per non-empty bucket)
    {
        int b = t;
        if (hist[b]) gbase[b] = b * BCAP + atomicAdd(&gcur[b], hist[b]);
        b = t + 256;
        if (hist[b]) gbase[b] = b * BCAP + atomicAdd(&gcur[b], hist[b]);
    }
    // exclusive scan over 512 bins: pair-sum (256) -> inclusive ladder -> expand
    s2[t] = hist[2 * t] + hist[2 * t + 1];
    __syncthreads();
    #pragma unroll
    for (int d = 1; d < 256; d <<= 1) {
        int u = (t >= d) ? s2[t - d] : 0;
        __syncthreads();
        s2[t] += u;
        __syncthreads();
    }
    {
        int b0 = (t > 0) ? s2[t - 1] : 0;
        lstart[2 * t] = b0;
        lstart[2 * t + 1] = b0 + hist[2 * t];
        lcur[2 * t] = b0;
        lcur[2 * t + 1] = b0 + hist[2 * t];
    }
    __syncthreads();
    // scatter into LDS, bucket-sorted; record global destination
    #pragma unroll
    for (int k = 0; k < PCHUNK / 256; ++k) {
        int idx = k * 256 + t;
        int e = e0 + idx;
        if (e < N_EDGES) {
            int c = (int)scol[idx];
            int b = c / BWID;
            int lp = atomicAdd(&lcur[b], 1);
            uint2 en;
            en.x = ((unsigned int)ei[e] << 16) | (unsigned int)f2bf(ew[e]);
            en.y = (unsigned int)(c - b * BWID);
            lent[lp] = en;
            unsigned int gd = (unsigned int)(gbase[b] + (lp - lstart[b]));
            ldst[lp] = (gd < (unsigned int)((b + 1) * BCAP)) ? gd : 0xFFFFFFFFu;
        }
    }
    __syncthreads();
    // coalesced write-out: consecutive threads -> consecutive dsts within runs
    for (int j = t; j < cnt; j += 256) {
        unsigned int gd = ldst[j];
        if (gd != 0xFFFFFFFFu) bkt[gd] = lent[j];
    }
}

// ---------------- per-bucket: deg + off + in-bucket sort (single global pass) --
__global__ __launch_bounds__(256) void k_bucket(const int* __restrict__ gcur,
                                                const uint2* __restrict__ bkt,
                                                int* __restrict__ deg,
                                                int* __restrict__ off,
                                                unsigned int* __restrict__ srt)
{
    __shared__ int hist[128];            // >= BWID
    __shared__ int lcur[128];
    __shared__ uint2 ent[BCAP];          // 16 KB: entries cached on first read
    __shared__ unsigned int stg[BCAP];   // 8 KB: sorted entries staged in LDS
    const int t = threadIdx.x;
    const int b = blockIdx.x;
    if (t < 128) hist[t] = 0;
    __syncthreads();
    const int cnt = min(gcur[b], BCAP);
    const uint2* base = bkt + (size_t)b * BCAP;
    for (int i = t; i < cnt; i += 256) {
        uint2 en = base[i];
        ent[i] = en;
        atomicAdd(&hist[en.y], 1);
    }
    __syncthreads();
    // exclusive scan over 128 — ALL threads execute every barrier (t>=128 idle)
    const int v = (t < 128) ? hist[t] : 0;
    #pragma unroll
    for (int d = 1; d < 128; d <<= 1) {
        int u = (t >= d && t < 128) ? hist[t - d] : 0;
        __syncthreads();
        if (t >= d && t < 128) hist[t] += u;
        __syncthreads();
    }
    if (t < 128) {
        int excl = hist[t] - v;
        lcur[t] = excl;
        if (t < BWID) {
            int col = b * BWID + t;
            if (col < N_NODES) {
                deg[col] = v;
                off[col] = b * BCAP + excl;
            }
        }
    }
    __syncthreads();
    for (int i = t; i < cnt; i += 256) {
        uint2 en = ent[i];
        int pos = atomicAdd(&lcur[en.y], 1);
        stg[pos] = en.x;            // row<<16 | bf16(w), sorted by lcol in LDS
    }
    __syncthreads();
    unsigned int* sb = srt + (size_t)b * BCAP;
    for (int i = t; i < cnt; i += 256) sb[i] = stg[i];   // coalesced
}

// ---------------- vbar GEMM: barrier-free, per-wave K-halved staging ----------
// vbarh[n,d] = bf16( (sum_c Xs[n,c]*Wvbar[d,c] + bvbar[d]) * rsqrt(deg[n]) )
// vsumr[rep][d] += sum_n acc (pre-bias, UNSCALED) for the attention constant.
__global__ __launch_bounds__(256) void k_vbar(
    const float* __restrict__ Xs, const unsigned short* __restrict__ wvbar,
    const float* __restrict__ bvbar, const int* __restrict__ deg,
    unsigned short* __restrict__ vbarh, float* __restrict__ vsumr)
{
    __shared__ float lX[64 * 128];    // 32 KB: one K-half (128 cols), reused
    const int t = threadIdx.x;
    const int w = t >> 6;
    const int l = t & 63;
    const int ln = l & 15;
    const int q = l >> 4;
    const int n0 = blockIdx.x * 64;

    const char* Xc = (const char*)Xs;
    const bf16x8* Wf = (const bf16x8*)wvbar;        // frag-swizzled, L2-hot
    const unsigned int swzl = ((unsigned int)(ln & 7)) << 4;  // row=w*16+ln, w*16%8==0
    const char* lrow = (const char*)&lX[(w * 16 + ln) * 128];

    f32x4 acc[4];
    #pragma unroll
    for (int nf = 0; nf < 4; ++nf) acc[nf] = (f32x4){0.f, 0.f, 0.f, 0.f};

    #pragma unroll
    for (int h = 0; h < 2; ++h) {
        // --- stage half h: 8 calls/wave, each = 2 rows x 512 B (per-lane src) ---
        #pragma unroll
        for (int i = 0; i < 8; ++i) {
            int r = w * 16 + i * 2 + (l >> 5);          // per-lane row in tile
            int g = n0 + r;
            int gc = (g < N_NODES) ? g : 0;             // clamp OOB, masked later
            unsigned int off = ((unsigned int)((l & 31) * 16))
                             ^ (((unsigned int)(r & 7)) << 4);
            const void* src = Xc + (size_t)gc * 1024 + (unsigned int)(h * 512) + off;
            gld_lds16(src, &lX[(w * 16 + i * 2) * 128]);  // wave-uniform dest base
        }
        asm volatile("s_waitcnt vmcnt(0)" ::: "memory");  // per-wave drain only
        __builtin_amdgcn_sched_barrier(0);

        // --- compute this half: ks = h*4 + ks2 ---
        #pragma unroll
        for (int ks2 = 0; ks2 < 4; ++ks2) {
            unsigned int c0 = (unsigned int)(ks2 * 128 + q * 32);
            float4 xa = *(const float4*)(lrow + (c0 ^ swzl));
            float4 xb = *(const float4*)(lrow + ((c0 + 16u) ^ swzl));
            bf16x8 A;
            A[0] = (__bf16)xa.x; A[1] = (__bf16)xa.y;
            A[2] = (__bf16)xa.z; A[3] = (__bf16)xa.w;
            A[4] = (__bf16)xb.x; A[5] = (__bf16)xb.y;
            A[6] = (__bf16)xb.z; A[7] = (__bf16)xb.w;
            int ks = h * 4 + ks2;
            #pragma unroll
            for (int nf = 0; nf < 4; ++nf) {
                bf16x8 b = Wf[(ks * 4 + nf) * 64 + l];
                acc[nf] = __builtin_amdgcn_mfma_f32_16x16x32_bf16(A, b, acc[nf], 0, 0, 0);
            }
        }
        if (h == 0) {
            // all h0 LDS reads must retire before h1 overwrites the buffer
            asm volatile("s_waitcnt lgkmcnt(0)" ::: "memory");
            __builtin_amdgcn_sched_barrier(0);
        }
    }

    // epilogue: D[m = q*4+r4][n = ln]; write bf16 vbar pre-scaled by rsqrt(deg)
    float bvb[4];
    #pragma unroll
    for (int nf = 0; nf < 4; ++nf) bvb[nf] = bvbar[nf * 16 + ln];
    float psum[4] = {0.f, 0.f, 0.f, 0.f};
    #pragma unroll
    for (int r4 = 0; r4 < 4; ++r4) {
        int g = n0 + w * 16 + q * 4 + r4;
        bool ok = g < N_NODES;
        float sc = 0.f;
        if (ok) {
            float dg = (float)deg[g];
            sc = (dg > 0.f) ? __frsqrt_rn(dg) : 0.f;
        }
        #pragma unroll
        for (int nf = 0; nf < 4; ++nf) {
            if (ok) {
                vbarh[g * 64 + nf * 16 + ln] = f2bf((acc[nf][r4] + bvb[nf]) * sc);
                psum[nf] += acc[nf][r4];   // OOB rows excluded
            }
        }
    }
    // reduce over q-groups in-register (no LDS, no barrier), then 1 atomic/col
    #pragma unroll
    for (int nf = 0; nf < 4; ++nf) {
        float v = psum[nf];
        v += __shfl_xor(v, 16, 64);
        v += __shfl_xor(v, 32, 64);
        psum[nf] = v;
    }
    if (l < 16) {
        int rep = (blockIdx.x * 4 + w) & (NVS - 1);
        #pragma unroll
        for (int nf = 0; nf < 4; ++nf)
            atomicAdd(&vsumr[rep * 64 + nf * 16 + ln], psum[nf]);
    }
}

// ---------------- GCN gather: one wave per node, lane = d-channel ----------------
// out[n,d] = aconst[d] + rsqrt(deg[n]) * sum_e w_e * vbarh[row_e, d]
__global__ __launch_bounds__(256) void k_gather(
    const int* __restrict__ off, const int* __restrict__ deg,
    const unsigned int* __restrict__ srt, const unsigned short* __restrict__ vbarh,
    const float* __restrict__ vsumr, const float* __restrict__ bvbar,
    float* __restrict__ out)
{
    const int t = threadIdx.x;
    const int lane = t & 63;
    const int n = blockIdx.x * 4 + (t >> 6);          // grid: 12544 blocks -> 50176
    if (n >= N_NODES) return;                          // whole wave exits together
    const int e0 = off[n];
    const int dc = deg[n];
    const int e1 = e0 + dc;
    float acc = 0.f;
    int e = e0;
    for (; e + 7 < e1; e += 8) {                       // avg deg 16 -> ~2 rounds
        unsigned int p0 = srt[e];
        unsigned int p1 = srt[e + 1];
        unsigned int p2 = srt[e + 2];
        unsigned int p3 = srt[e + 3];
        unsigned int p4 = srt[e + 4];
        unsigned int p5 = srt[e + 5];
        unsigned int p6 = srt[e + 6];
        unsigned int p7 = srt[e + 7];
        float a0 = __uint_as_float(p0 << 16) * bf2f(vbarh[(p0 >> 16) * 64 + lane]);
        float a1 = __uint_as_float(p1 << 16) * bf2f(vbarh[(p1 >> 16) * 64 + lane]);
        float a2 = __uint_as_float(p2 << 16) * bf2f(vbarh[(p2 >> 16) * 64 + lane]);
        float a3 = __uint_as_float(p3 << 16) * bf2f(vbarh[(p3 >> 16) * 64 + lane]);
        float a4 = __uint_as_float(p4 << 16) * bf2f(vbarh[(p4 >> 16) * 64 + lane]);
        float a5 = __uint_as_float(p5 << 16) * bf2f(vbarh[(p5 >> 16) * 64 + lane]);
        float a6 = __uint_as_float(p6 << 16) * bf2f(vbarh[(p6 >> 16) * 64 + lane]);
        float a7 = __uint_as_float(p7 << 16) * bf2f(vbarh[(p7 >> 16) * 64 + lane]);
        acc += ((a0 + a1) + (a2 + a3)) + ((a4 + a5) + (a6 + a7));
    }
    for (; e < e1; ++e) {
        unsigned int p = srt[e];
        acc += __uint_as_float(p << 16) * bf2f(vbarh[(p >> 16) * 64 + lane]);
    }
    float dcf = (float)dc;
    float scn = (dcf > 0.f) ? __frsqrt_rn(dcf) : 0.f;
    float vs = 0.f;
    #pragma unroll
    for (int i = 0; i < NVS; ++i) vs += vsumr[i * 64 + lane];
    float aconst = vs * (1.0f / (float)N_NODES) + bvbar[lane];
    out[n * 64 + lane] = acc * scn + aconst;
}

extern "C" void kernel_launch(void* const* d_in, const int* in_sizes, int n_in,
                              void* d_out, int out_size, void* d_ws, size_t ws_size,
                              hipStream_t stream)
{
    const float* Xs = (const float*)d_in[1];   // source_input [N,256]
    const float* Wv = (const float*)d_in[6];   // Wv_w [256,256]
    const float* bv = (const float*)d_in[7];   // Wv_b [256]
    const int*   ei = (const int*)d_in[8];     // edge_index [2,E]
    const float* ew = (const float*)d_in[9];   // edge_weight [E]
    float* out = (float*)d_out;                // [N,64]

    unsigned short* vbarh = (unsigned short*)d_ws;               // 3.2M bf16 (6.4 MB)
    uint2* bkt  = (uint2*)(vbarh + (size_t)N_NODES * 64);        // 512*2048*8 = 8.39 MB
    unsigned int* srt = (unsigned int*)(bkt + (size_t)NBUK * BCAP); // 4.19 MB
    unsigned short* wvbar = (unsigned short*)(srt + (size_t)NBUK * BCAP); // 32 KB
    float* bvbar   = (float*)(wvbar + 16384);                    // 64
    float* vsumr   = bvbar + 64;                                 // 32 x 64 replicas
    int*   gcur    = (int*)(vsumr + NVS * 64);                   // 512
    int*   deg     = gcur + NBUK;                                // 50,000
    int*   off     = deg + N_NODES;                              // 50,000

    // k_wprep also zeroes gcur + vsumr (replaces the hipMemsetAsync dispatch)
    k_wprep<<<16, 256, 0, stream>>>(Wv, bv, wvbar, bvbar, gcur, vsumr);
    k_part<<<PBLK, 256, 0, stream>>>(ei, ew, gcur, bkt);
    k_bucket<<<NBUK, 256, 0, stream>>>(gcur, bkt, deg, off, srt);
    k_vbar<<<(N_NODES + 63) / 64, 256, 0, stream>>>(Xs, wvbar, bvbar, deg, vbarh, vsumr);
    k_gather<<<(NBUK * BWID) / 4, 256, 0, stream>>>(off, deg, srt, vbarh, vsumr, bvbar, out);
}